// Round 11
// baseline (184.810 us; speedup 1.0000x reference)
//
#include <hip/hip_runtime.h>
#include <hip/hip_bf16.h>

#define NF     32
#define ED     128
#define NBATCH 2048
#define NPAIRS 496

typedef __attribute__((ext_vector_type(8))) short short8;   // 8 bf16 = 16 B
typedef __attribute__((ext_vector_type(4))) short short4v;  // 4 bf16 = 8 B
typedef __attribute__((ext_vector_type(4))) float f32x4;

#define FEMB_BF_ELEMS ((size_t)NF * NBATCH * ED)            // 8,388,608
#define W_BF_ELEMS    ((size_t)NPAIRS * ED * ED)            // 8,126,464
#define WS_NEEDED     ((FEMB_BF_ELEMS + W_BF_ELEMS) * 2)    // ~33 MB

__device__ __forceinline__ short f2bf(float x) {
    union { __hip_bfloat16 b; short s; } v;
    v.b = __float2bfloat16(x);
    return v.s;
}
__device__ __forceinline__ float bf2f(short s) {
    union { unsigned int u; float f; } v;
    v.u = ((unsigned int)(unsigned short)s) << 16;
    return v.f;
}

// ---------- Pre-pass 1: femb fp32 [b][f][d] -> bf16 field-major [f][b][d] ----------
__global__ __launch_bounds__(256)
void prep_femb(const float* __restrict__ femb, unsigned short* __restrict__ fb) {
    int n = blockIdx.x * 256 + threadIdx.x;       // 1,048,576 threads x 8 elems
    int d8 = n & 15;
    int b  = (n >> 4) & (NBATCH - 1);
    int f  = n >> 15;
    const float* s = femb + ((size_t)b * NF + f) * ED + d8 * 8;
    f32x4 lo = __builtin_nontemporal_load(reinterpret_cast<const f32x4*>(s));
    f32x4 hi = __builtin_nontemporal_load(reinterpret_cast<const f32x4*>(s + 4));
    short8 pk;
    pk[0]=f2bf(lo.x); pk[1]=f2bf(lo.y); pk[2]=f2bf(lo.z); pk[3]=f2bf(lo.w);
    pk[4]=f2bf(hi.x); pk[5]=f2bf(hi.y); pk[6]=f2bf(hi.z); pk[7]=f2bf(hi.w);
    *reinterpret_cast<short8*>(fb + ((size_t)f * NBATCH + b) * ED + d8 * 8) = pk;
}

// ---------- Pre-pass 2: W fp32 [p][e][d] -> bf16 FRAGMENT-MAJOR ----------
// wswz[p][etile(8)][kk(4)][lane(64)][8 bf16]: a wave's MFMA A-fragment
// (e = etile*16 + llo, d = kk*32 + lhi*8 ..+7) is ONE coalesced 1KB load.
__global__ __launch_bounds__(256)
void prep_w_swz(const float* __restrict__ W, unsigned short* __restrict__ wswz) {
    int n = blockIdx.x * 256 + threadIdx.x;       // 1,015,808 threads
    int lane  = n & 63;
    int kk    = (n >> 6) & 3;
    int etile = (n >> 8) & 7;
    int p     = n >> 11;
    int e  = etile * 16 + (lane & 15);
    int d0 = kk * 32 + (lane >> 4) * 8;
    const float* s = W + (size_t)p * (ED * ED) + (size_t)e * ED + d0;
    f32x4 lo = __builtin_nontemporal_load(reinterpret_cast<const f32x4*>(s));
    f32x4 hi = __builtin_nontemporal_load(reinterpret_cast<const f32x4*>(s + 4));
    short8 pk;
    pk[0]=f2bf(lo.x); pk[1]=f2bf(lo.y); pk[2]=f2bf(lo.z); pk[3]=f2bf(lo.w);
    pk[4]=f2bf(hi.x); pk[5]=f2bf(hi.y); pk[6]=f2bf(hi.z); pk[7]=f2bf(hi.w);
    *reinterpret_cast<short8*>(wswz + (size_t)n * 8) = pk;
}

// ---------- Main kernel: registers-only streaming, no LDS, no barriers ----------
// Grid 1024 = 16 pair-chunks (31 consecutive pairs) x 64 b-chunks (32 rows).
// XCD-grouped: pair-chunks {2x, 2x+1} -> XCD x; its 128 resident blocks share
// a 2MB L2-hot W slice. vi fragments persist in registers across pairs with
// the same fi (lexicographic bands -> reload ~1-2x per block). Per b-row the
// 31 pairs' 512B output chunks are written temporally adjacent.
__global__ __launch_bounds__(256, 4)
void bilinear_stream(const unsigned short* __restrict__ fb,
                     const unsigned short* __restrict__ wswz,
                     float* __restrict__ out)
{
    const int bid = blockIdx.x;
    const int xcd = bid & 7;
    const int idx = bid >> 3;               // 0..127
    const int pc  = xcd * 2 + (idx >> 6);   // pair-chunk 0..15
    const int bc  = idx & 63;               // b-chunk 0..63
    const int p0  = pc * 31;
    const int b0  = bc * 32;

    const int t    = threadIdx.x;           // 0..255, 4 waves
    const int lane = t & 63;
    const int wid  = t >> 6;                // wave: e-tiles {2*wid, 2*wid+1}
    const int lhi  = lane >> 4;
    const int llo  = lane & 15;

    // initial (fi, fj) for p0
    int fi = 0, rem = p0;
    while (rem >= NF - 1 - fi) { rem -= NF - 1 - fi; ++fi; }
    int fj = fi + 1 + rem;

    // vi fragments in registers: [ni(2 b-tiles)][kk(4)], b = b0 + ni*16 + llo,
    // d = kk*32 + lhi*8. 16B/lane, 16 rows x 64B -> full-line accesses.
    short8 vi[2][4];
    int cur_fi = -1;

    for (int pp = 0; pp < 31; ++pp) {
        const int p = p0 + pp;

        if (fi != cur_fi) {
            const unsigned short* fiP = fb + (size_t)fi * NBATCH * ED;
            #pragma unroll
            for (int ni = 0; ni < 2; ++ni)
                #pragma unroll
                for (int kk = 0; kk < 4; ++kk)
                    vi[ni][kk] = *reinterpret_cast<const short8*>(
                        fiP + (size_t)(b0 + ni * 16 + llo) * ED + kk * 32 + lhi * 8);
            cur_fi = fi;
        }

        const unsigned short* wp  = wswz + (size_t)p * (ED * ED);
        const unsigned short* fjP = fb + (size_t)fj * NBATCH * ED;

        // vj fragments (epilogue operand): e = (2*wid+et)*16 + lhi*4 ..+3
        short4v vjr[2][2];
        #pragma unroll
        for (int et = 0; et < 2; ++et)
            #pragma unroll
            for (int ni = 0; ni < 2; ++ni)
                vjr[et][ni] = *reinterpret_cast<const short4v*>(
                    fjP + (size_t)(b0 + ni * 16 + llo) * ED + (2 * wid + et) * 16 + lhi * 4);

        // ---- D[e][b] = W . vi^T : 16 MFMA, W frags coalesced from L2 ----
        f32x4 acc[2][2] = {};
        #pragma unroll
        for (int kk = 0; kk < 4; ++kk) {
            short8 a[2];
            #pragma unroll
            for (int et = 0; et < 2; ++et)
                a[et] = *reinterpret_cast<const short8*>(
                    wp + ((size_t)((2 * wid + et) * 4 + kk) * 64 + lane) * 8);
            #pragma unroll
            for (int et = 0; et < 2; ++et)
                #pragma unroll
                for (int ni = 0; ni < 2; ++ni)
                    acc[et][ni] = __builtin_amdgcn_mfma_f32_16x16x32_bf16(
                        a[et], vi[ni][kk], acc[et][ni], 0, 0, 0);
        }

        // ---- Epilogue: out[b][p][e] = D * vj, NT float4 stores ----
        // D frag: row(e-local) = lhi*4+q, col(b) = llo. Per instr: 16 rows x
        // one full 64B line. Consecutive pp -> adjacent 512B chunks per row.
        #pragma unroll
        for (int et = 0; et < 2; ++et) {
            #pragma unroll
            for (int ni = 0; ni < 2; ++ni) {
                int b  = b0 + ni * 16 + llo;
                int e0 = (2 * wid + et) * 16 + lhi * 4;
                float* op = out + ((size_t)b * NPAIRS + p) * ED + e0;
                short4v vs = vjr[et][ni];
                f32x4 r = acc[et][ni];
                f32x4 o;
                o.x = r[0] * bf2f(vs[0]); o.y = r[1] * bf2f(vs[1]);
                o.z = r[2] * bf2f(vs[2]); o.w = r[3] * bf2f(vs[3]);
                __builtin_nontemporal_store(o, reinterpret_cast<f32x4*>(op));
            }
        }

        // advance lexicographic (fi, fj)
        ++fj;
        if (fj == NF) { ++fi; fj = fi + 1; }
    }
}

// ---------- Fallback (fp32 inputs, r7-style LDS path) if ws too small ----------
__global__ __launch_bounds__(512, 2)
void bilinear_f32(const float* __restrict__ femb,
                  const float* __restrict__ W,
                  float* __restrict__ out)
{
    __shared__ unsigned char ldsW[128 * 256];
    __shared__ unsigned char ldsA[128 * 256];

    const int p = blockIdx.x;
    int fi = 0, rem = p;
    while (rem >= NF - 1 - fi) { rem -= NF - 1 - fi; ++fi; }
    const int fj = fi + 1 + rem;

    const int t    = threadIdx.x;
    const int lane = t & 63;
    const int wave = t >> 6;

    {
        const float* wp = W + (size_t)p * (ED * ED);
        #pragma unroll
        for (int it = 0; it < 4; ++it) {
            int idx8 = it * 4096 + t * 8;
            int e = idx8 >> 7, d = idx8 & 127;
            const float* s = wp + (size_t)e * ED + d;
            f32x4 lo = __builtin_nontemporal_load(reinterpret_cast<const f32x4*>(s));
            f32x4 hi = __builtin_nontemporal_load(reinterpret_cast<const f32x4*>(s + 4));
            short8 pk;
            pk[0]=f2bf(lo.x); pk[1]=f2bf(lo.y); pk[2]=f2bf(lo.z); pk[3]=f2bf(lo.w);
            pk[4]=f2bf(hi.x); pk[5]=f2bf(hi.y); pk[6]=f2bf(hi.z); pk[7]=f2bf(hi.w);
            *reinterpret_cast<short8*>(ldsW + e * 256 + ((d * 2) ^ ((e & 15) << 4))) = pk;
        }
    }

    const int r_ = t >> 4;
    const int d_ = (t * 8) & 127;
    const size_t ROWSTRIDE32 = (size_t)32 * NF * ED;

    const int we  = wave & 3;
    const int wb_ = wave >> 2;
    const int lhi = lane >> 4;
    const int llo = lane & 15;

    f32x4 stg[8];
    {
        const float* base = femb + ((size_t)r_ * NF + fi) * ED + d_;
        #pragma unroll
        for (int q = 0; q < 4; ++q) {
            const float* s = base + (size_t)q * ROWSTRIDE32;
            stg[2*q]   = *reinterpret_cast<const f32x4*>(s);
            stg[2*q+1] = *reinterpret_cast<const f32x4*>(s + 4);
        }
    }

    for (int mb = 0; mb < NBATCH / 128; ++mb) {
        const int b0 = mb * 128;
        #pragma unroll
        for (int q = 0; q < 4; ++q) {
            int r = r_ + q * 32;
            f32x4 lo = stg[2*q], hi = stg[2*q+1];
            short8 pk;
            pk[0]=f2bf(lo.x); pk[1]=f2bf(lo.y); pk[2]=f2bf(lo.z); pk[3]=f2bf(lo.w);
            pk[4]=f2bf(hi.x); pk[5]=f2bf(hi.y); pk[6]=f2bf(hi.z); pk[7]=f2bf(hi.w);
            *reinterpret_cast<short8*>(ldsA + r * 256 + ((d_ * 2) ^ ((r & 15) << 4))) = pk;
        }
        __syncthreads();

        if (mb + 1 < NBATCH / 128) {
            const float* base = femb + ((size_t)((mb + 1) * 128 + r_) * NF + fi) * ED + d_;
            #pragma unroll
            for (int q = 0; q < 4; ++q) {
                const float* s = base + (size_t)q * ROWSTRIDE32;
                stg[2*q]   = *reinterpret_cast<const f32x4*>(s);
                stg[2*q+1] = *reinterpret_cast<const f32x4*>(s + 4);
            }
        }

        f32x4 vjr[4][2];
        #pragma unroll
        for (int ni = 0; ni < 4; ++ni) {
            int b = b0 + wb_ * 64 + ni * 16 + llo;
            const float* vj = femb + ((size_t)b * NF + fj) * ED;
            #pragma unroll
            for (int mi = 0; mi < 2; ++mi) {
                int e0 = we * 32 + mi * 16 + lhi * 4;
                vjr[ni][mi] = *reinterpret_cast<const f32x4*>(vj + e0);
            }
        }

        f32x4 acc[2][4] = {};
        #pragma unroll
        for (int kk = 0; kk < 4; ++kk) {
            const int db = kk * 64 + lhi * 16;
            short8 a[2], b[4];
            #pragma unroll
            for (int mi = 0; mi < 2; ++mi) {
                int e = we * 32 + mi * 16 + llo;
                a[mi] = *reinterpret_cast<const short8*>(ldsW + e * 256 + (db ^ (llo << 4)));
            }
            #pragma unroll
            for (int ni = 0; ni < 4; ++ni) {
                int r = wb_ * 64 + ni * 16 + llo;
                b[ni] = *reinterpret_cast<const short8*>(ldsA + r * 256 + (db ^ (llo << 4)));
            }
            #pragma unroll
            for (int mi = 0; mi < 2; ++mi)
                #pragma unroll
                for (int ni = 0; ni < 4; ++ni)
                    acc[mi][ni] = __builtin_amdgcn_mfma_f32_16x16x32_bf16(a[mi], b[ni], acc[mi][ni], 0, 0, 0);
        }
        __syncthreads();

        #pragma unroll
        for (int ni = 0; ni < 4; ++ni) {
            int b = b0 + wb_ * 64 + ni * 16 + llo;
            float* op = out + ((size_t)b * NPAIRS + p) * ED;
            #pragma unroll
            for (int mi = 0; mi < 2; ++mi) {
                int e0 = we * 32 + mi * 16 + lhi * 4;
                f32x4 v = vjr[ni][mi];
                f32x4 r = acc[mi][ni];
                f32x4 o;
                o.x = r[0] * v.x; o.y = r[1] * v.y;
                o.z = r[2] * v.z; o.w = r[3] * v.w;
                __builtin_nontemporal_store(o, reinterpret_cast<f32x4*>(op + e0));
            }
        }
    }
}

extern "C" void kernel_launch(void* const* d_in, const int* in_sizes, int n_in,
                              void* d_out, int out_size, void* d_ws, size_t ws_size,
                              hipStream_t stream) {
    (void)in_sizes; (void)n_in; (void)out_size;
    const float* femb = (const float*)d_in[0];
    const float* W    = (const float*)d_in[1];
    float* out        = (float*)d_out;

    if (ws_size >= WS_NEEDED) {
        unsigned short* fbp = (unsigned short*)d_ws;
        unsigned short* wsz = fbp + FEMB_BF_ELEMS;
        hipLaunchKernelGGL(prep_femb, dim3(FEMB_BF_ELEMS / 8 / 256), dim3(256), 0, stream, femb, fbp);
        hipLaunchKernelGGL(prep_w_swz, dim3(W_BF_ELEMS / 8 / 256), dim3(256), 0, stream, W, wsz);
        hipLaunchKernelGGL(bilinear_stream, dim3(1024), dim3(256), 0, stream, fbp, wsz, out);
    } else {
        hipLaunchKernelGGL(bilinear_f32, dim3(NPAIRS), dim3(512), 0, stream, femb, W, out);
    }
}